// Round 3
// baseline (3047.303 us; speedup 1.0000x reference)
//
#include <hip/hip_runtime.h>

// ---------------------------------------------------------------------------
// MattingSolver CG on MI355X — round 3: atomic-minimal setup + streaming it2.
//
// R2 evidence: atomic throughput ~22G/s caps k_hist (7.2M atomics, 317us) and
// k_fill (~4.35M). Changes:
//  * Per-edge identities fold ALL row-sums into products:
//      Lv[i]  = sum_e cv_e (p_i - p_col)        (no rs_cm prepass)
//      u'_a   = sum_b w_ab (p_a - p_b)          (no Dall prepass)
//    -> hist pass counts only (4.35M atomics), rs_cm computed free in k_it1.
//  * Push-based products: setup stores DESTINATION slots (dPos/dIdx*); k_it1
//    writes products to gather-sorted positions (plain scattered stores);
//    k_it2 reads prod/gath fully CONTIGUOUSLY -> pure streaming kernel.
//  * Lazy p: p_t(j) = r_t[j] + beta_t * p_{t-1}[j] recomputed at gathers
//    (ping-pong p buffers); k_it3 eliminated -> 2 kernels/iter, 66 launches.
// scal: [0]=1.0, [1]=0.0, rs_t at [2+t], pAp_t at [40+t].
// ---------------------------------------------------------------------------

#define TPB 256

__device__ __forceinline__ float blockReduce256(float v) {
  #pragma unroll
  for (int o = 32; o > 0; o >>= 1) v += __shfl_down(v, o, 64);
  __shared__ float s[4];
  int lane = threadIdx.x & 63, wv = threadIdx.x >> 6;
  if (lane == 0) s[wv] = v;
  __syncthreads();
  return (threadIdx.x == 0) ? (s[0] + s[1] + s[2] + s[3]) : 0.f;
}

// vectors, diag, b, scal, CNT zero, b.b  (grid: 3*Bn)
__global__ void k_init0(const float* __restrict__ KUw, const float* __restrict__ kToUconf,
                        const float* __restrict__ lmbda, const float* __restrict__ known,
                        const float* __restrict__ kToU,
                        float* __restrict__ diag_ku, float* __restrict__ r,
                        float* __restrict__ p0, float* __restrict__ x,
                        int* __restrict__ CNT, float* __restrict__ scal, int N)
{
  int i = blockIdx.x * TPB + threadIdx.x;
  if (i < 80) scal[i] = (i == 0) ? 1.f : 0.f;
  if (i < 3 * N) CNT[i] = 0;
  float red = 0.f;
  if (i < N) {
    float dk = KUw[i] * kToUconf[i] + lmbda[0] * known[i];
    diag_ku[i] = dk;
    float b = dk * kToU[i];
    r[i] = b; p0[i] = 0.f; x[i] = 0.f;
    red = b * b;
  }
  float v = blockReduce256(red);
  if (threadIdx.x == 0) atomicAdd(&scal[2], v);
}

// histograms only (4.35M atomics)  (grid: Bz + 2*Bl)
__global__ void k_hist(const int* __restrict__ Wrow, const int* __restrict__ Wcol,
                       const int* __restrict__ LOC_inInd, const int* __restrict__ width_p,
                       const int* __restrict__ IU_inInd, const int* __restrict__ IU_neighInd,
                       int* __restrict__ CNT,
                       int NLOC, int N, int B0, int B1)
{
  int blk = blockIdx.x;
  if (blk < B0) {                       // CM row + col counts
    int e = blk * TPB + threadIdx.x;
    atomicAdd(&CNT[Wrow[e]], 1);
    atomicAdd(&CNT[N + Wcol[e]], 1);
  } else if (blk < B1) {                // Wm gather-row counts
    int k = (blk - B0) * TPB + threadIdx.x;
    int wd = *width_p;
    int base = LOC_inInd[k];
    const int offs[9] = {-1 - wd, -1, -1 + wd, -wd, 0, wd, 1 - wd, 1, 1 + wd};
    #pragma unroll
    for (int a = 0; a < 9; ++a) atomicAdd(&CNT[2 * N + base + offs[a]], 1);
  } else {                              // Wc gather-row counts
    int k = (blk - B1) * TPB + threadIdx.x;
    int r0 = IU_inInd[k];
    #pragma unroll
    for (int j = 0; j < 5; ++j) {
      atomicAdd(&CNT[2 * N + r0], 1);
      atomicAdd(&CNT[2 * N + IU_neighInd[k * 5 + j]], 1);
    }
  }
}

__global__ void k_scan1(const int* __restrict__ CNT, int* __restrict__ OFF,
                        int* __restrict__ bsum, int tot)
{
  __shared__ int s[TPB];
  int gid = blockIdx.x * TPB + threadIdx.x;
  int v = (gid < tot) ? CNT[gid] : 0;
  s[threadIdx.x] = v;
  __syncthreads();
  #pragma unroll
  for (int o = 1; o < TPB; o <<= 1) {
    int t = (threadIdx.x >= o) ? s[threadIdx.x - o] : 0;
    __syncthreads();
    s[threadIdx.x] += t;
    __syncthreads();
  }
  if (gid < tot) OFF[gid] = s[threadIdx.x] - v;
  if (threadIdx.x == TPB - 1) bsum[blockIdx.x] = s[threadIdx.x];
}

__global__ void k_scan2(int* __restrict__ bsum, int nPerArr)  // 3 blocks x 1024
{
  __shared__ int s[1024];
  int base = blockIdx.x * nPerArr;
  int v = (threadIdx.x < nPerArr) ? bsum[base + threadIdx.x] : 0;
  s[threadIdx.x] = v;
  __syncthreads();
  for (int o = 1; o < 1024; o <<= 1) {
    int t = (threadIdx.x >= o) ? s[threadIdx.x - o] : 0;
    __syncthreads();
    s[threadIdx.x] += t;
    __syncthreads();
  }
  if (threadIdx.x < nPerArr) bsum[base + threadIdx.x] = s[threadIdx.x] - v;
}

__global__ void k_scan3(int* __restrict__ OFF, int* __restrict__ CUR,
                        const int* __restrict__ bsum, int tot)
{
  int gid = blockIdx.x * TPB + threadIdx.x;
  if (gid < tot) {
    int o = OFF[gid] + bsum[blockIdx.x];
    OFF[gid] = o;
    CUR[gid] = o;
  }
}

// fill CSR(+csc destination slots) and product-destination indices
__global__ void k_fill(const float* __restrict__ CMw, const float* __restrict__ Wcm_data,
                       const int* __restrict__ Wrow, const int* __restrict__ Wcol,
                       const int* __restrict__ LOC_inInd, const int* __restrict__ width_p,
                       const int* __restrict__ IU_inInd, const int* __restrict__ IU_neighInd,
                       int* __restrict__ CUR,
                       int* __restrict__ csr_col, float* __restrict__ csr_val,
                       int* __restrict__ dPos,
                       int* __restrict__ dIdxWm, int* __restrict__ dIdxA, int* __restrict__ dIdxB,
                       int NLOC, int N, int B0, int B1)
{
  int blk = blockIdx.x;
  if (blk < B0) {                       // CM: CSR entry + CSC destination slot
    int e = blk * TPB + threadIdx.x;
    int row = Wrow[e], col = Wcol[e];
    float cv = CMw[row] * Wcm_data[e];
    int pr = atomicAdd(&CUR[row], 1);
    csr_col[pr] = col; csr_val[pr] = cv;
    int pc = atomicAdd(&CUR[N + col], 1);
    dPos[pr] = pc;
  } else if (blk < B1) {                // Wm: destination in gath
    int k = (blk - B0) * TPB + threadIdx.x;
    int wd = *width_p;
    int base = LOC_inInd[k];
    const int offs[9] = {-1 - wd, -1, -1 + wd, -wd, 0, wd, 1 - wd, 1, 1 + wd};
    #pragma unroll
    for (int a = 0; a < 9; ++a)
      dIdxWm[a * NLOC + k] = atomicAdd(&CUR[2 * N + base + offs[a]], 1);
  } else {                              // Wc: two destinations per edge
    int k = (blk - B1) * TPB + threadIdx.x;
    int r0 = IU_inInd[k];
    #pragma unroll
    for (int j = 0; j < 5; ++j) {
      int c0 = IU_neighInd[k * 5 + j];
      dIdxA[j * NLOC + k] = atomicAdd(&CUR[2 * N + r0], 1);
      dIdxB[j * NLOC + k] = atomicAdd(&CUR[2 * N + c0], 1);
    }
  }
}

// pass 1: lazy-p, products pushed to sorted slots, Lv, rs_cm, full pAp
// grid: Bl (Wm) + Bl (Wc) + Bn (CSR)
__global__ void k_it1(const float* __restrict__ r, const float* __restrict__ pold,
                      float* __restrict__ pnew,
                      const float* __restrict__ bnum, const float* __restrict__ bden,
                      const float* __restrict__ LOC_flows, const int* __restrict__ LOC_inInd,
                      const float* __restrict__ LOCw, const int* __restrict__ width_p,
                      const float* __restrict__ IU_flows, const int* __restrict__ IU_inInd,
                      const int* __restrict__ IU_neighInd, const float* __restrict__ IUw,
                      const float* __restrict__ diag_ku,
                      const int* __restrict__ OFF,
                      const int* __restrict__ csr_col, const float* __restrict__ csr_val,
                      const int* __restrict__ dPos,
                      const int* __restrict__ dIdxWm, const int* __restrict__ dIdxA,
                      const int* __restrict__ dIdxB,
                      float* __restrict__ gath, float* __restrict__ prod,
                      float* __restrict__ Lv, float* __restrict__ rs_cm,
                      float* __restrict__ pAp_t,
                      int NNZ, int NLOC, int N, int B0, int B1)
{
  int blk = blockIdx.x;
  float beta = bnum[0] / bden[0];
  float red = 0.f;
  if (blk < B0) {                       // Wm: u'_a = sum_b w_ab (p_a - p_b)
    int k = blk * TPB + threadIdx.x;
    int wd = *width_p;
    int base = LOC_inInd[k];
    float hw = 0.5f * LOCw[base];
    const int offs[9] = {-1 - wd, -1, -1 + wd, -wd, 0, wd, 1 - wd, 1, 1 + wd};
    float pv[9];
    #pragma unroll
    for (int a = 0; a < 9; ++a) {
      int j = base + offs[a];
      pv[a] = r[j] + beta * pold[j];
    }
    float Fl[81];
    #pragma unroll
    for (int m = 0; m < 81; ++m) Fl[m] = LOC_flows[(size_t)m * NLOC + k];
    float qf = 0.f;
    #pragma unroll
    for (int a = 0; a < 9; ++a) {
      float u = 0.f;
      #pragma unroll
      for (int b = 0; b < 9; ++b) u += (Fl[b * 9 + a] + Fl[a * 9 + b]) * (pv[a] - pv[b]);
      u *= hw;
      gath[dIdxWm[a * NLOC + k]] = u;
      qf += u * pv[a];
    }
    red = qf;
  } else if (blk < B1) {                // Wc: uA = w (p_r0 - p_c0)
    int k = (blk - B0) * TPB + threadIdx.x;
    int r0 = IU_inInd[k];
    float hw = 0.5f * IUw[r0];
    float pr = r[r0] + beta * pold[r0];
    float qf = 0.f;
    #pragma unroll
    for (int j = 0; j < 5; ++j) {
      float w = hw * IU_flows[k * 5 + j];
      int c0 = IU_neighInd[k * 5 + j];
      float pc = r[c0] + beta * pold[c0];
      float d = pr - pc;
      float uA = w * d;
      gath[dIdxA[j * NLOC + k]] = uA;
      gath[dIdxB[j * NLOC + k]] = -uA;
      qf += uA * d;
    }
    red = qf;
  } else {                              // CSR: p materialize, Lv, rs_cm, prod push
    int i = (blk - B1) * TPB + threadIdx.x;
    float pi = r[i] + beta * pold[i];
    pnew[i] = pi;
    int s = OFF[i];
    int e = (i == N - 1) ? NNZ : OFF[i + 1];
    float acc = 0.f, rs = 0.f;
    for (int q = s; q < e; ++q) {
      float cv = csr_val[q];
      int c = csr_col[q];
      rs += cv;
      acc += cv * (pi - (r[c] + beta * pold[c]));
    }
    Lv[i] = acc;
    rs_cm[i] = rs;
    for (int q = s; q < e; ++q) prod[dPos[q]] = csr_val[q] * acc;
    red = diag_ku[i] * pi * pi + acc * acc;
  }
  float v = blockReduce256(red);
  if (threadIdx.x == 0) atomicAdd(pAp_t, v);
}

// pass 2: fully streaming Ap assembly + x/r update + r.r
__global__ void k_it2(float* __restrict__ x, float* __restrict__ r,
                      const float* __restrict__ pt, const float* __restrict__ Lv,
                      const float* __restrict__ rs_cm, const float* __restrict__ diag_ku,
                      const int* __restrict__ OFF,
                      const float* __restrict__ prod, const float* __restrict__ gath,
                      const float* __restrict__ rs_t, const float* __restrict__ pAp_t,
                      float* __restrict__ rs_t1,
                      int NNZ, int NG, int N)
{
  int i = blockIdx.x * TPB + threadIdx.x;
  float alpha = rs_t[0] / pAp_t[0];
  float tg = 0.f;
  {
    int s = OFF[2 * N + i];
    int e = (i == N - 1) ? NG : OFF[2 * N + i + 1];
    for (int q = s; q < e; ++q) tg += gath[q];
  }
  float sc = 0.f;
  {
    int s = OFF[N + i];
    int e = (i == N - 1) ? NNZ : OFF[N + i + 1];
    for (int q = s; q < e; ++q) sc += prod[q];
  }
  float pi = pt[i];
  float Ap = diag_ku[i] * pi + rs_cm[i] * Lv[i] - sc + tg;
  x[i] += alpha * pi;
  float rn = r[i] - alpha * Ap;
  r[i] = rn;
  float v = blockReduce256(rn * rn);
  if (threadIdx.x == 0) atomicAdd(rs_t1, v);
}

extern "C" void kernel_launch(void* const* d_in, const int* in_sizes, int n_in,
                              void* d_out, int out_size, void* d_ws, size_t ws_size,
                              hipStream_t stream)
{
  const float* CMw       = (const float*)d_in[0];
  const float* LOCw      = (const float*)d_in[1];
  const float* IUw       = (const float*)d_in[2];
  const float* KUw       = (const float*)d_in[3];
  const float* lmbda     = (const float*)d_in[4];
  const float* kToUconf  = (const float*)d_in[5];
  const float* known     = (const float*)d_in[6];
  const float* kToU      = (const float*)d_in[7];
  const float* Wcm_data  = (const float*)d_in[8];
  const float* LOC_flows = (const float*)d_in[9];
  const float* IU_flows  = (const float*)d_in[10];
  const int*   Wrow      = (const int*)d_in[11];
  const int*   Wcol      = (const int*)d_in[12];
  const int*   LOC_inInd = (const int*)d_in[13];
  const int*   IU_inInd  = (const int*)d_in[14];
  const int*   IU_neighInd = (const int*)d_in[15];
  const int*   width_p   = (const int*)d_in[16];
  const int CG_STEPS = 30;

  const int N    = in_sizes[0];      // 147456 (% 256 == 0)
  const int NNZ  = in_sizes[8];      // 1474560
  const int NLOC = in_sizes[13];     // 73728
  const int NG   = 19 * NLOC;

  float* x       = (float*)d_out;
  float* r       = (float*)d_ws;
  float* pb0     = r + N;
  float* pb1     = pb0 + N;
  float* Lv      = pb1 + N;
  float* rs_cm   = Lv + N;
  float* diag_ku = rs_cm + N;
  float* csr_val = diag_ku + N;                 // NNZ
  float* prod    = csr_val + (size_t)NNZ;       // NNZ
  float* gath    = prod + (size_t)NNZ;          // NG
  int*   csr_col = (int*)(gath + (size_t)NG);   // NNZ
  int*   dPos    = csr_col + (size_t)NNZ;       // NNZ
  int*   dIdxWm  = dPos + (size_t)NNZ;          // 9*NLOC
  int*   dIdxA   = dIdxWm + (size_t)9 * NLOC;   // 5*NLOC
  int*   dIdxB   = dIdxA + (size_t)5 * NLOC;    // 5*NLOC
  int*   CNT     = dIdxB + (size_t)5 * NLOC;    // 3N
  int*   OFF     = CNT + (size_t)3 * N;         // 3N
  int*   CUR     = OFF + (size_t)3 * N;         // 3N
  int*   bsum    = CUR + (size_t)3 * N;         // 3*(N/256)
  float* scal    = (float*)(bsum + 3 * (N / TPB));

  const int Bn = N / TPB;        // 576
  const int Bz = NNZ / TPB;      // 5760
  const int Bl = NLOC / TPB;     // 288
  const int Z3 = 3 * Bn;

  k_init0<<<Z3, TPB, 0, stream>>>(KUw, kToUconf, lmbda, known, kToU,
                                  diag_ku, r, pb0, x, CNT, scal, N);
  k_hist<<<Bz + 2 * Bl, TPB, 0, stream>>>(Wrow, Wcol, LOC_inInd, width_p,
                                          IU_inInd, IU_neighInd, CNT,
                                          NLOC, N, Bz, Bz + Bl);
  k_scan1<<<Z3, TPB, 0, stream>>>(CNT, OFF, bsum, 3 * N);
  k_scan2<<<3, 1024, 0, stream>>>(bsum, Bn);
  k_scan3<<<Z3, TPB, 0, stream>>>(OFF, CUR, bsum, 3 * N);
  k_fill<<<Bz + 2 * Bl, TPB, 0, stream>>>(CMw, Wcm_data, Wrow, Wcol,
                                          LOC_inInd, width_p, IU_inInd, IU_neighInd,
                                          CUR, csr_col, csr_val, dPos,
                                          dIdxWm, dIdxA, dIdxB,
                                          NLOC, N, Bz, Bz + Bl);

  float* pbuf[2] = {pb0, pb1};
  for (int t = 0; t < CG_STEPS; ++t) {
    const float* pold = pbuf[t & 1];
    float* pnew = pbuf[(t + 1) & 1];
    const float* bnum = (t == 0) ? scal + 1 : scal + 2 + t;
    const float* bden = (t == 0) ? scal + 0 : scal + 1 + t;
    k_it1<<<2 * Bl + Bn, TPB, 0, stream>>>(
        r, pold, pnew, bnum, bden,
        LOC_flows, LOC_inInd, LOCw, width_p,
        IU_flows, IU_inInd, IU_neighInd, IUw,
        diag_ku, OFF, csr_col, csr_val, dPos, dIdxWm, dIdxA, dIdxB,
        gath, prod, Lv, rs_cm, scal + 40 + t,
        NNZ, NLOC, N, Bl, 2 * Bl);
    k_it2<<<Bn, TPB, 0, stream>>>(
        x, r, pnew, Lv, rs_cm, diag_ku, OFF, prod, gath,
        scal + 2 + t, scal + 40 + t, scal + 3 + t, NNZ, NG, N);
  }
}